// Round 2
// baseline (85.715 us; speedup 1.0000x reference)
//
#include <hip/hip_runtime.h>

#define NBINS 5

typedef float f32x4 __attribute__((ext_vector_type(4)));

__global__ __launch_bounds__(256) void ToneMapping_kernel(
    const float* __restrict__ x,
    const float* __restrict__ widths,
    const float* __restrict__ heights,
    const float* __restrict__ slopes,
    float* __restrict__ out,
    long long n4, long long n)
{
    // Packed per-bin spline params, 2x float4 per bin -> 2 ds_read_b128/elem.
    // Bank pattern: each array spans 5*4=20 words < 32 banks -> conflict-free
    // (lanes with equal idx broadcast).
    __shared__ float4 s_pA[NBINS]; // {x_low, 1/(xh-xl+1e-8), y_low, y_high-y_low}
    __shared__ float4 s_pB[NBINS]; // {slope_low-2, s, 2*(s-2), pad}
    __shared__ float  s_edge[NBINS - 1];

    if (threadIdx.x == 0) {
        // Sequential f32 cumsum in the same order as jnp.cumsum.
        float c = 0.0f;
        for (int i = 0; i < NBINS; ++i) {
            float w  = widths[i];
            float xl = c;              // widths_cumsum[i]
            c = c + w;                 // edges[i]
            if (i < NBINS - 1) s_edge[i] = c;
            float xh = xl + w;         // (widths_cumsum + widths)[i]
            float yl = heights[i], yh = heights[i + 1];
            float sl = slopes[i],  sh = slopes[i + 1];
            float ss = sl + sh;
            s_pA[i] = make_float4(xl, 1.0f / (xh - xl + 1e-8f), yl, yh - yl);
            s_pB[i] = make_float4(sl - 2.0f, ss, 2.0f * (ss - 2.0f), 0.0f);
        }
    }
    __syncthreads();

    // Hoist bin edges to registers (4 ds_reads once per thread).
    float e0 = s_edge[0], e1 = s_edge[1], e2 = s_edge[2], e3 = s_edge[3];

    long long tid    = (long long)blockIdx.x * blockDim.x + threadIdx.x;
    long long stride = (long long)gridDim.x * blockDim.x;

    const f32x4* __restrict__ x4 = (const f32x4*)x;
    f32x4* __restrict__ o4 = (f32x4*)out;

    auto evalv = [&](f32x4 v) -> f32x4 {
        f32x4 r;
        #pragma unroll
        for (int k = 0; k < 4; ++k) {
            float xf = fminf(fmaxf(v[k], 0.0f), 1.0f);
            // searchsorted(edges, xf, 'left') clipped to 4 == count(edges[0..3] < xf)
            int idx = (int)(e0 < xf) + (int)(e1 < xf) + (int)(e2 < xf) + (int)(e3 < xf);
            float4 pA = s_pA[idx];   // ds_read_b128
            float4 pB = s_pB[idx];   // ds_read_b128
            float t   = (xf - pA.x) * pA.y;
            float t2  = t * t;
            float num = fmaf(t2, pB.x, t + t);                     // sl*t^2 + 2t(1-t)
            float den = fmaf(pB.y, t2, fmaf(pB.z, t, 2.0f));       // s*t^2 + 2(s-2)t + 2
            r[k] = fmaf(pA.w, num * __builtin_amdgcn_rcpf(den), pA.z);
        }
        return r;
    };

    long long i = tid;
    const long long step4 = 4 * stride;
    // 4x unrolled: 4 independent 16B loads in flight per wave iteration.
    for (; i + 3 * stride < n4; i += step4) {
        f32x4 v0 = __builtin_nontemporal_load(x4 + i);
        f32x4 v1 = __builtin_nontemporal_load(x4 + i + stride);
        f32x4 v2 = __builtin_nontemporal_load(x4 + i + 2 * stride);
        f32x4 v3 = __builtin_nontemporal_load(x4 + i + 3 * stride);
        f32x4 r0 = evalv(v0);
        f32x4 r1 = evalv(v1);
        f32x4 r2 = evalv(v2);
        f32x4 r3 = evalv(v3);
        __builtin_nontemporal_store(r0, o4 + i);
        __builtin_nontemporal_store(r1, o4 + i + stride);
        __builtin_nontemporal_store(r2, o4 + i + 2 * stride);
        __builtin_nontemporal_store(r3, o4 + i + 3 * stride);
    }
    for (; i < n4; i += stride) {
        f32x4 v = __builtin_nontemporal_load(x4 + i);
        __builtin_nontemporal_store(evalv(v), o4 + i);
    }

    // Scalar tail (n % 4 != 0) — not hit for this shape, kept for generality.
    long long ts = n4 * 4;
    for (long long j = ts + tid; j < n; j += stride) {
        float xf = fminf(fmaxf(x[j], 0.0f), 1.0f);
        int idx = (int)(e0 < xf) + (int)(e1 < xf) + (int)(e2 < xf) + (int)(e3 < xf);
        float4 pA = s_pA[idx];
        float4 pB = s_pB[idx];
        float t   = (xf - pA.x) * pA.y;
        float t2  = t * t;
        float num = fmaf(t2, pB.x, t + t);
        float den = fmaf(pB.y, t2, fmaf(pB.z, t, 2.0f));
        out[j] = fmaf(pA.w, num * __builtin_amdgcn_rcpf(den), pA.z);
    }
}

extern "C" void kernel_launch(void* const* d_in, const int* in_sizes, int n_in,
                              void* d_out, int out_size, void* d_ws, size_t ws_size,
                              hipStream_t stream) {
    const float* x       = (const float*)d_in[0];
    const float* widths  = (const float*)d_in[1];
    const float* heights = (const float*)d_in[2];
    const float* slopes  = (const float*)d_in[3];
    float* out = (float*)d_out;

    long long n  = (long long)in_sizes[0];
    long long n4 = n / 4;

    const int block = 256;
    long long want = (n4 + block - 1) / block;
    int grid = (int)(want < 2048 ? (want > 0 ? want : 1) : 2048);

    ToneMapping_kernel<<<grid, block, 0, stream>>>(x, widths, heights, slopes, out, n4, n);
}

// Round 3
// 83.997 us; speedup vs baseline: 1.0204x; 1.0204x over previous
//
#include <hip/hip_runtime.h>

#define NBINS 5

typedef float f32x4 __attribute__((ext_vector_type(4)));

__global__ __launch_bounds__(256) void ToneMapping_kernel(
    const float* __restrict__ x,
    const float* __restrict__ widths,
    const float* __restrict__ heights,
    const float* __restrict__ slopes,
    float* __restrict__ out,
    long long n4, long long n)
{
    // Packed per-bin spline params: 2x ds_read_b128 per element.
    // 5 idx values -> disjoint bank groups (idx*4 .. idx*4+3), conflict-free;
    // equal-idx lanes broadcast.
    __shared__ float4 s_pA[NBINS]; // {x_low, 1/(xh-xl+1e-8), y_low, y_high-y_low}
    __shared__ float4 s_pB[NBINS]; // {slope_low-2, s, 2*(s-2), pad}
    __shared__ float  s_edge[NBINS - 1];

    if (threadIdx.x == 0) {
        // Sequential f32 cumsum, same order as jnp.cumsum -> identical rounding.
        float c = 0.0f;
        for (int i = 0; i < NBINS; ++i) {
            float w  = widths[i];
            float xl = c;              // widths_cumsum[i]
            c = c + w;                 // edges[i]
            if (i < NBINS - 1) s_edge[i] = c;
            float xh = xl + w;
            float yl = heights[i], yh = heights[i + 1];
            float sl = slopes[i],  sh = slopes[i + 1];
            float ss = sl + sh;
            s_pA[i] = make_float4(xl, 1.0f / (xh - xl + 1e-8f), yl, yh - yl);
            s_pB[i] = make_float4(sl - 2.0f, ss, 2.0f * (ss - 2.0f), 0.0f);
        }
    }
    __syncthreads();

    // Bin edges in registers.
    float e0 = s_edge[0], e1 = s_edge[1], e2 = s_edge[2], e3 = s_edge[3];

    const f32x4* __restrict__ x4 = (const f32x4*)x;
    f32x4* __restrict__ o4 = (f32x4*)out;

    auto evalv = [&](f32x4 v) -> f32x4 {
        f32x4 r;
        #pragma unroll
        for (int k = 0; k < 4; ++k) {
            float xf = fminf(fmaxf(v[k], 0.0f), 1.0f);
            // searchsorted(edges, xf, 'left') clipped == count(edges[0..3] < xf)
            int idx = (int)(e0 < xf) + (int)(e1 < xf) + (int)(e2 < xf) + (int)(e3 < xf);
            float4 pA = s_pA[idx];   // ds_read_b128
            float4 pB = s_pB[idx];   // ds_read_b128
            float t   = (xf - pA.x) * pA.y;
            float t2  = t * t;
            float num = fmaf(t2, pB.x, t + t);                 // sl*t^2 + 2t(1-t)
            float den = fmaf(pB.y, t2, fmaf(pB.z, t, 2.0f));   // s*t^2 + 2(s-2)t + 2
            r[k] = fmaf(pA.w, num * __builtin_amdgcn_rcpf(den), pA.z);
        }
        return r;
    };

    const long long bd     = blockDim.x;                    // 256
    const long long nthr   = (long long)gridDim.x * bd;     // total threads
    const long long chunk  = 2 * nthr;                      // float4s per grid pass

    // Main loop: each thread handles 2 block-contiguous float4s per pass.
    // Both loads are wave-coalesced; the pair stays within a 16KB window.
    long long off = (long long)blockIdx.x * (2 * bd) + threadIdx.x;
    const long long pair_stride = 2 * bd * (long long)gridDim.x; // == chunk
    for (long long base = off; base + bd < n4 + 1 && base + bd < n4 ? false : false; ) {} // (unused)

    long long full_passes = n4 / chunk;
    long long main_end    = full_passes * chunk;

    for (long long p = 0; p < full_passes; ++p) {
        long long base = p * chunk + (long long)blockIdx.x * (2 * bd) + threadIdx.x;
        f32x4 v0 = x4[base];
        f32x4 v1 = x4[base + bd];
        f32x4 r0 = evalv(v0);
        f32x4 r1 = evalv(v1);
        o4[base]      = r0;
        o4[base + bd] = r1;
    }

    // Tail float4s (n4 % chunk) — grid-stride single loop.
    for (long long i = main_end + (long long)blockIdx.x * bd + threadIdx.x;
         i < n4; i += nthr) {
        o4[i] = evalv(x4[i]);
    }

    // Scalar tail (n % 4) — not hit for this shape.
    long long ts = n4 * 4;
    for (long long j = ts + (long long)blockIdx.x * bd + threadIdx.x; j < n; j += nthr) {
        float xf = fminf(fmaxf(x[j], 0.0f), 1.0f);
        int idx = (int)(e0 < xf) + (int)(e1 < xf) + (int)(e2 < xf) + (int)(e3 < xf);
        float4 pA = s_pA[idx];
        float4 pB = s_pB[idx];
        float t   = (xf - pA.x) * pA.y;
        float t2  = t * t;
        float num = fmaf(t2, pB.x, t + t);
        float den = fmaf(pB.y, t2, fmaf(pB.z, t, 2.0f));
        out[j] = fmaf(pA.w, num * __builtin_amdgcn_rcpf(den), pA.z);
    }
}

extern "C" void kernel_launch(void* const* d_in, const int* in_sizes, int n_in,
                              void* d_out, int out_size, void* d_ws, size_t ws_size,
                              hipStream_t stream) {
    const float* x       = (const float*)d_in[0];
    const float* widths  = (const float*)d_in[1];
    const float* heights = (const float*)d_in[2];
    const float* slopes  = (const float*)d_in[3];
    float* out = (float*)d_out;

    long long n  = (long long)in_sizes[0];
    long long n4 = n / 4;

    const int block = 256;
    long long want = (n4 / 2 + block - 1) / block;  // 2 float4s per thread per pass
    int grid = (int)(want < 2048 ? (want > 0 ? want : 1) : 2048);

    ToneMapping_kernel<<<grid, block, 0, stream>>>(x, widths, heights, slopes, out, n4, n);
}